// Round 1
// baseline (5389.623 us; speedup 1.0000x reference)
//
#include <hip/hip_runtime.h>
#include <math.h>

#define TT 1024
#define U1 128
#define U2 32
#define NCOL 480   // 384 rk1 gate-cols + 96 k2 cols (both dot against h1)
#define NQ 120     // long-col quads
#define NUQ 4      // u-quarters

__device__ __forceinline__ float fast_tanh(float v) {
    float e = __expf(2.f * v);      // v>>0: e=inf -> 1; v<<0: e=0 -> -1 (NaN-free)
    return 1.f - 2.f / (e + 1.f);
}
__device__ __forceinline__ float fast_sig(float v) {
    return 1.f / (1.f + __expf(-v));
}

// 512 blocks x 512 threads; block owns batch blockIdx.x; 2 blocks/CU so one
// block's barrier/LDS-latency stalls overlap the other block's FMA issue.
// Dot phase (t<504, uniform branch-free loop): thread owns 4 consecutive
//   columns and a 32-long u-range; per float4 broadcast LDS read -> 16 FMAs.
//   t<480: cols 4q..4q+3 of [rk1|k2] vs h1 (u-quarter uq=t/120).
//   480<=t<504: cols of rk2 vs h2 (u=0..31 full).
// Update phase: t<128 GRU1 unit update (h_old in reg); t 128..159 GRU2
//   update lagged one step. 2 barriers/step.
__global__ __launch_bounds__(512, 4)
void gru_stack_kernel(const float* __restrict__ x,   // [512,1024,1]
                      const float* __restrict__ k1,  // [1,384]
                      const float* __restrict__ rk1, // [128,384]
                      const float* __restrict__ b1,  // [2,384]
                      const float* __restrict__ k2,  // [128,96]
                      const float* __restrict__ rk2, // [32,96]
                      const float* __restrict__ b2,  // [2,96]
                      const float* __restrict__ wd,  // [32,1]
                      const float* __restrict__ bd,  // [1]
                      float* __restrict__ out)       // [512,1]
{
    __shared__ __align__(16) float h1s[U1];
    __shared__ __align__(16) float h2s[U2];
    __shared__ __align__(16) float part1[NUQ][NCOL];  // [uq][col]
    __shared__ __align__(16) float part2[96];         // rk2 partials

    const int t = threadIdx.x;
    const int b = blockIdx.x;

    if (t < U1) h1s[t] = 0.f;
    if (t < U2) h2s[t] = 0.f;

    // ---------------- dot-role setup ----------------
    float4 w4[32];                      // weights for 4 cols x 32 u
    const float4* pb = nullptr;         // h source
    float4* pd = nullptr;               // partial dest
    const bool is_dot = (t < 504);
    if (t < 480) {
        const int uq = t / NQ, q = t % NQ;
        const int c0 = 4 * q, ub = 32 * uq;
#pragma unroll
        for (int j = 0; j < 32; ++j) {
            const int u = ub + j;
            float vv[4];
#pragma unroll
            for (int r = 0; r < 4; ++r) {
                const int c = c0 + r;
                vv[r] = (c < 384) ? rk1[u * 384 + c] : k2[u * 96 + (c - 384)];
            }
            w4[j] = make_float4(vv[0], vv[1], vv[2], vv[3]);
        }
        pb = (const float4*)&h1s[ub];
        pd = (float4*)&part1[uq][c0];
    } else if (t < 504) {
        const int q2 = t - 480, c0 = 4 * q2;
#pragma unroll
        for (int j = 0; j < 32; ++j)
            w4[j] = make_float4(rk2[j * 96 + c0 + 0], rk2[j * 96 + c0 + 1],
                                rk2[j * 96 + c0 + 2], rk2[j * 96 + c0 + 3]);
        pb = (const float4*)&h2s[0];
        pd = (float4*)&part2[c0];
    }

    // ---------------- update-role setup ----------------
    const int ju = t & 127;                            // t<128: GRU1 update
    float k1z = 0, k1r = 0, k1h = 0, bz = 0, br = 0, bhx = 0, bhr = 0, h_old = 0;
    if (t < 128) {
        k1z = k1[ju]; k1r = k1[128 + ju]; k1h = k1[256 + ju];
        bz  = b1[ju]       + b1[384 + ju];
        br  = b1[128 + ju] + b1[384 + 128 + ju];
        bhx = b1[256 + ju];
        bhr = b1[384 + 256 + ju];
    }
    const int j2 = (t - 128) & 31;                     // t 128..159: GRU2 update
    float bz2 = 0, br2 = 0, bh2x = 0, bh2r = 0, h2_old = 0;
    if (t >= 128 && t < 160) {
        bz2  = b2[j2]      + b2[96 + j2];
        br2  = b2[32 + j2] + b2[96 + 32 + j2];
        bh2x = b2[64 + j2];
        bh2r = b2[96 + 64 + j2];
    }

    __syncthreads();  // B0: h init visible

    for (int i = 0; i <= TT; ++i) {
        float xv = 0.f;
        if (t < 128 && i < TT) xv = x[b * TT + i];

        if (is_dot) {
            float4 a = make_float4(0.f, 0.f, 0.f, 0.f);
#pragma unroll
            for (int j4 = 0; j4 < 8; ++j4) {
                float4 hv = pb[j4];
                float ha[4] = {hv.x, hv.y, hv.z, hv.w};
#pragma unroll
                for (int e = 0; e < 4; ++e) {
                    const float4 wv = w4[4 * j4 + e];
                    const float he = ha[e];
                    a.x = fmaf(he, wv.x, a.x);
                    a.y = fmaf(he, wv.y, a.y);
                    a.z = fmaf(he, wv.z, a.z);
                    a.w = fmaf(he, wv.w, a.w);
                }
            }
            *pd = a;
        }
        __syncthreads();  // B1: partials visible

        if (t < 128 && i < TT) {
            // GRU1 unit update: z/r = relu, hh = tanh (reset_after)
            float iz = part1[0][ju] + part1[1][ju]
                     + part1[2][ju] + part1[3][ju];
            float ir = part1[0][128 + ju] + part1[1][128 + ju]
                     + part1[2][128 + ju] + part1[3][128 + ju];
            float ih = part1[0][256 + ju] + part1[1][256 + ju]
                     + part1[2][256 + ju] + part1[3][256 + ju];
            float z  = fmaxf(fmaf(xv, k1z, bz) + iz, 0.f);
            float r  = fmaxf(fmaf(xv, k1r, br) + ir, 0.f);
            float hh = fast_tanh(fmaf(xv, k1h, bhx) + r * (ih + bhr));
            h_old = fmaf(z, h_old - hh, hh);
            h1s[ju] = h_old;
        } else if (t >= 128 && t < 160 && i >= 1) {
            // GRU2 unit update (one step behind): z/r = sigmoid, hh = relu
            float xz = part1[0][384 + j2] + part1[1][384 + j2]
                     + part1[2][384 + j2] + part1[3][384 + j2];
            float xr = part1[0][416 + j2] + part1[1][416 + j2]
                     + part1[2][416 + j2] + part1[3][416 + j2];
            float xh = part1[0][448 + j2] + part1[1][448 + j2]
                     + part1[2][448 + j2] + part1[3][448 + j2];
            float iz = part2[j2];
            float ir = part2[32 + j2];
            float ih = part2[64 + j2];
            float z  = fast_sig(xz + iz + bz2);
            float r  = fast_sig(xr + ir + br2);
            float hh = fmaxf(xh + bh2x + r * (ih + bh2r), 0.f);
            h2_old = fmaf(z, h2_old - hh, hh);
            h2s[j2] = h2_old;
        }
        __syncthreads();  // B2: h updated
    }

    // ---------------- dense head ----------------
    if (t < 32) {
        float p = h2s[t] * wd[t];
#pragma unroll
        for (int m = 16; m >= 1; m >>= 1) p += __shfl_xor(p, m, 64);
        if (t == 0) out[b] = p + bd[0];
    }
}

extern "C" void kernel_launch(void* const* d_in, const int* in_sizes, int n_in,
                              void* d_out, int out_size, void* d_ws, size_t ws_size,
                              hipStream_t stream) {
    const float* x   = (const float*)d_in[0];
    const float* k1  = (const float*)d_in[1];
    const float* rk1 = (const float*)d_in[2];
    const float* b1  = (const float*)d_in[3];
    const float* k2  = (const float*)d_in[4];
    const float* rk2 = (const float*)d_in[5];
    const float* b2  = (const float*)d_in[6];
    const float* wd  = (const float*)d_in[7];
    const float* bd  = (const float*)d_in[8];
    float* out = (float*)d_out;

    dim3 grid(512), block(512);
    hipLaunchKernelGGL(gru_stack_kernel, grid, block, 0, stream,
                       x, k1, rk1, b1, k2, rk2, b2, wd, bd, out);
}

// Round 2
// 1142.703 us; speedup vs baseline: 4.7166x; 4.7166x over previous
//
#include <hip/hip_runtime.h>
#include <math.h>

#define TT 1024
#define U1 128
#define U2 32
#define NCOL 480   // 384 rk1 gate-cols + 96 k2 cols (both dot against h1)
#define NCP 240    // long col-pairs
#define NUQ 4      // u-quarters

__device__ __forceinline__ float fast_tanh(float v) {
    float e = __expf(2.f * v);      // v>>0: e=inf -> 1; v<<0: e=0 -> -1 (NaN-free)
    return 1.f - 2.f / (e + 1.f);
}
__device__ __forceinline__ float fast_sig(float v) {
    return 1.f / (1.f + __expf(-v));
}

// 256 blocks x 1024 threads; block owns batches {2b, 2b+1}; 1 block/CU but
// 4 waves/SIMD (vs 2 in the 512-thread version) to hide intra-phase LDS
// latency. Weights/thread halve to 64 floats (float2 w2[32]) so the
// 128-VGPR cap forced by the 1024-thread block still fits (est ~108).
// Dot phase: thread owns 2 consecutive columns and a 32-long u-range;
//   per float4 broadcast LDS read -> 8 FMAs (x2 batches).
//   t<960: cols 2p..2p+1 of [rk1|k2] vs h1 (u-quarter uq=t/240).
//   960<=t<1008: col-pairs of rk2 vs h2 (u=0..31 full).
// Update phase: t<256 GRU1 unit update (h_old in reg); t 256..319 GRU2
//   update lagged one step. 2 barriers/step.
__global__ __launch_bounds__(1024)
void gru_stack_kernel(const float* __restrict__ x,   // [512,1024,1]
                      const float* __restrict__ k1,  // [1,384]
                      const float* __restrict__ rk1, // [128,384]
                      const float* __restrict__ b1,  // [2,384]
                      const float* __restrict__ k2,  // [128,96]
                      const float* __restrict__ rk2, // [32,96]
                      const float* __restrict__ b2,  // [2,96]
                      const float* __restrict__ wd,  // [32,1]
                      const float* __restrict__ bd,  // [1]
                      float* __restrict__ out)       // [512,1]
{
    __shared__ __align__(16) float h1s[2][U1];
    __shared__ __align__(16) float h2s[2][U2];
    __shared__ __align__(16) float part1[2][NUQ][NCOL];  // [b][uq][col]
    __shared__ __align__(16) float part2[2][96];         // rk2 partials

    const int t  = threadIdx.x;
    const int b0 = blockIdx.x * 2;

    if (t < 2 * U1) ((float*)h1s)[t] = 0.f;
    if (t < 2 * U2) ((float*)h2s)[t] = 0.f;

    // ---------------- dot-role setup ----------------
    float2 w2[32];                      // 64 VGPRs: weights for 2 cols x 32 u
    const float4* pb0 = nullptr;        // h source, batch 0
    const float4* pb1 = nullptr;        // h source, batch 1
    float2* pd0 = nullptr;              // partial dest, batch 0
    float2* pd1 = nullptr;
    const bool is_dot = (t < 1008);
    if (t < 960) {
        const int uq = t / NCP, p = t % NCP;
        const int c0 = 2 * p, ub = 32 * uq;
#pragma unroll
        for (int j = 0; j < 32; ++j) {
            const int u = ub + j;
            float vv[2];
#pragma unroll
            for (int r = 0; r < 2; ++r) {
                const int c = c0 + r;
                vv[r] = (c < 384) ? rk1[u * 384 + c] : k2[u * 96 + (c - 384)];
            }
            w2[j] = make_float2(vv[0], vv[1]);
        }
        pb0 = (const float4*)&h1s[0][ub];
        pb1 = (const float4*)&h1s[1][ub];
        pd0 = (float2*)&part1[0][uq][c0];
        pd1 = (float2*)&part1[1][uq][c0];
    } else if (t < 1008) {
        const int q2 = t - 960, c0 = 2 * q2;
#pragma unroll
        for (int j = 0; j < 32; ++j)
            w2[j] = make_float2(rk2[j * 96 + c0 + 0], rk2[j * 96 + c0 + 1]);
        pb0 = (const float4*)&h2s[0][0];
        pb1 = (const float4*)&h2s[1][0];
        pd0 = (float2*)&part2[0][c0];
        pd1 = (float2*)&part2[1][c0];
    }

    // ---------------- update-role setup ----------------
    const int ju = t & 127, bu = t >> 7;               // t<256: GRU1 update
    float k1z = 0, k1r = 0, k1h = 0, bz = 0, br = 0, bhx = 0, bhr = 0, h_old = 0;
    if (t < 256) {
        k1z = k1[ju]; k1r = k1[128 + ju]; k1h = k1[256 + ju];
        bz  = b1[ju]       + b1[384 + ju];
        br  = b1[128 + ju] + b1[384 + 128 + ju];
        bhx = b1[256 + ju];
        bhr = b1[384 + 256 + ju];
    }
    const int tau = t - 256, j2 = tau & 31, bb2 = tau >> 5;  // t 256..319: GRU2 update
    float bz2 = 0, br2 = 0, bh2x = 0, bh2r = 0, h2_old = 0;
    if (t >= 256 && t < 320) {
        bz2  = b2[j2]      + b2[96 + j2];
        br2  = b2[32 + j2] + b2[96 + 32 + j2];
        bh2x = b2[64 + j2];
        bh2r = b2[96 + 64 + j2];
    }

    __syncthreads();  // B0: h init visible

    for (int i = 0; i <= TT; ++i) {
        float xv = 0.f;
        if (t < 256 && i < TT) xv = x[(b0 + bu) * TT + i];

        if (is_dot) {
            float2 a0 = make_float2(0.f, 0.f);
            float2 a1 = make_float2(0.f, 0.f);
#pragma unroll
            for (int j4 = 0; j4 < 8; ++j4) {
                float4 hv0 = pb0[j4];
                float4 hv1 = pb1[j4];
                float ha0[4] = {hv0.x, hv0.y, hv0.z, hv0.w};
                float ha1[4] = {hv1.x, hv1.y, hv1.z, hv1.w};
#pragma unroll
                for (int e = 0; e < 4; ++e) {
                    const float2 wv = w2[4 * j4 + e];
                    const float he0 = ha0[e], he1 = ha1[e];
                    a0.x = fmaf(he0, wv.x, a0.x);
                    a0.y = fmaf(he0, wv.y, a0.y);
                    a1.x = fmaf(he1, wv.x, a1.x);
                    a1.y = fmaf(he1, wv.y, a1.y);
                }
            }
            *pd0 = a0;
            *pd1 = a1;
        }
        __syncthreads();  // B1: partials visible

        if (t < 256 && i < TT) {
            // GRU1 unit update: z/r = relu, hh = tanh (reset_after)
            float iz = part1[bu][0][ju] + part1[bu][1][ju]
                     + part1[bu][2][ju] + part1[bu][3][ju];
            float ir = part1[bu][0][128 + ju] + part1[bu][1][128 + ju]
                     + part1[bu][2][128 + ju] + part1[bu][3][128 + ju];
            float ih = part1[bu][0][256 + ju] + part1[bu][1][256 + ju]
                     + part1[bu][2][256 + ju] + part1[bu][3][256 + ju];
            float z  = fmaxf(fmaf(xv, k1z, bz) + iz, 0.f);
            float r  = fmaxf(fmaf(xv, k1r, br) + ir, 0.f);
            float hh = fast_tanh(fmaf(xv, k1h, bhx) + r * (ih + bhr));
            h_old = fmaf(z, h_old - hh, hh);
            h1s[bu][ju] = h_old;
        } else if (t >= 256 && t < 320 && i >= 1) {
            // GRU2 unit update (one step behind): z/r = sigmoid, hh = relu
            float xz = part1[bb2][0][384 + j2] + part1[bb2][1][384 + j2]
                     + part1[bb2][2][384 + j2] + part1[bb2][3][384 + j2];
            float xr = part1[bb2][0][416 + j2] + part1[bb2][1][416 + j2]
                     + part1[bb2][2][416 + j2] + part1[bb2][3][416 + j2];
            float xh = part1[bb2][0][448 + j2] + part1[bb2][1][448 + j2]
                     + part1[bb2][2][448 + j2] + part1[bb2][3][448 + j2];
            float iz = part2[bb2][j2];
            float ir = part2[bb2][32 + j2];
            float ih = part2[bb2][64 + j2];
            float z  = fast_sig(xz + iz + bz2);
            float r  = fast_sig(xr + ir + br2);
            float hh = fmaxf(xh + bh2x + r * (ih + bh2r), 0.f);
            h2_old = fmaf(z, h2_old - hh, hh);
            h2s[bb2][j2] = h2_old;
        }
        __syncthreads();  // B2: h updated
    }

    // ---------------- dense head ----------------
    if (t < 64) {
        const int b = t >> 5, j = t & 31;
        float p = h2s[b][j] * wd[j];
#pragma unroll
        for (int m = 16; m >= 1; m >>= 1) p += __shfl_xor(p, m, 64);
        if (j == 0) out[b0 + b] = p + bd[0];
    }
}

extern "C" void kernel_launch(void* const* d_in, const int* in_sizes, int n_in,
                              void* d_out, int out_size, void* d_ws, size_t ws_size,
                              hipStream_t stream) {
    const float* x   = (const float*)d_in[0];
    const float* k1  = (const float*)d_in[1];
    const float* rk1 = (const float*)d_in[2];
    const float* b1  = (const float*)d_in[3];
    const float* k2  = (const float*)d_in[4];
    const float* rk2 = (const float*)d_in[5];
    const float* b2  = (const float*)d_in[6];
    const float* wd  = (const float*)d_in[7];
    const float* bd  = (const float*)d_in[8];
    float* out = (float*)d_out;

    dim3 grid(256), block(1024);
    hipLaunchKernelGGL(gru_stack_kernel, grid, block, 0, stream,
                       x, k1, rk1, b1, k2, rk2, b2, wd, bd, out);
}